// Round 5
// baseline (3609.528 us; speedup 1.0000x reference)
//
#include <hip/hip_runtime.h>

typedef unsigned int u32;
typedef unsigned short u16;
typedef __attribute__((ext_vector_type(8))) short short8;   // 8 x bf16 (guide-verified frag type)
typedef __attribute__((ext_vector_type(4))) float f32x4;

__device__ __forceinline__ u16 f2bf(float f) {
    u32 u = __float_as_uint(f);
    u32 r = (u + 0x7fffu + ((u >> 16) & 1u)) >> 16;   // RNE
    return (u16)r;
}
__device__ __forceinline__ float bf2f(u32 lo16) { return __uint_as_float(lo16 << 16); }

// ---------------- prep kernels ----------------

__global__ __launch_bounds__(256) void cvt_f2b(const float* __restrict__ x,
                                               u16* __restrict__ xb, size_t n4) {
    size_t i = (size_t)blockIdx.x * 256 + threadIdx.x;
    if (i >= n4) return;
    float4 v = ((const float4*)x)[i];
    u32 lo = (u32)f2bf(v.x) | ((u32)f2bf(v.y) << 16);
    u32 hi = (u32)f2bf(v.z) | ((u32)f2bf(v.w) << 16);
    ((uint2*)xb)[i] = make_uint2(lo, hi);
}

// fused transposed weights for all 3 layers in one launch
__global__ __launch_bounds__(256) void prep_w_all(const float* __restrict__ ws0, const float* __restrict__ wn0, u16* __restrict__ wt0,
                                                  const float* __restrict__ ws1, const float* __restrict__ wn1, u16* __restrict__ wt1,
                                                  const float* __restrict__ ws2, const float* __restrict__ wn2, u16* __restrict__ wt2) {
    int bid = blockIdx.x;
    const float *ws, *wn;
    u16* wt;
    int dout, HW, local;
    if (bid < 128)      { ws = ws0; wn = wn0; wt = wt0; dout = 128; HW = 128; local = bid; }
    else if (bid < 256) { ws = ws1; wn = wn1; wt = wt1; dout = 128; HW = 128; local = bid - 128; }
    else                { ws = ws2; wn = wn2; wt = wt2; dout = 47;  HW = 64;  local = bid - 256; }
    int idx = local * 256 + threadIdx.x;   // idx = n*128 + k
    int n = idx >> 7, k = idx & 127;
    float v = 0.f;
    if (n < HW) { if (n < dout) v = ws[k * dout + n]; }
    else { int nn = n - HW; if (nn < dout) v = wn[k * dout + nn]; }
    wt[idx] = f2bf(v);
}

// ---------------- CSR-bucket build (128-node buckets) ----------------

__global__ __launch_bounds__(256) void hist_k(const int* __restrict__ dst,
                                              int* __restrict__ deg, int E) {
    int i = blockIdx.x * 256 + threadIdx.x;
    if (i < E) atomicAdd(&deg[dst[i]], 1);
}

__global__ __launch_bounds__(256) void scan_partial(const int* __restrict__ deg,
                                                    int* __restrict__ bsum, int Nn) {
    __shared__ int sm[256];
    int t = threadIdx.x;
    int base = blockIdx.x * 1024 + t * 4;
    int s = 0;
#pragma unroll
    for (int j = 0; j < 4; j++)
        if (base + j < Nn) s += deg[base + j];
    sm[t] = s;
    __syncthreads();
    for (int off = 128; off > 0; off >>= 1) {
        if (t < off) sm[t] += sm[t + off];
        __syncthreads();
    }
    if (t == 0) bsum[blockIdx.x] = sm[0];
}

__global__ __launch_bounds__(256) void scan_offsets(const int* __restrict__ bsum,
                                                    int* __restrict__ boff, int nb) {
    __shared__ int sm[256];
    int t = threadIdx.x;
    int v = (t < nb) ? bsum[t] : 0;
    sm[t] = v;
    __syncthreads();
    for (int off = 1; off < 256; off <<= 1) {
        int u = (t >= off) ? sm[t - off] : 0;
        __syncthreads();
        sm[t] += u;
        __syncthreads();
    }
    if (t < nb) boff[t] = sm[t] - v;
}

// rowptr + invd + bucket cursor init (cursor[b] = rowptr[b*128])
__global__ __launch_bounds__(1024) void scan_final(const int* __restrict__ deg,
                                                   const int* __restrict__ boff,
                                                   int* __restrict__ rowptr,
                                                   float* __restrict__ invd,
                                                   int* __restrict__ cursor,
                                                   int Nn, int E) {
    __shared__ int sm[1024];
    int t = threadIdx.x;
    int i = blockIdx.x * 1024 + t;
    int v = (i < Nn) ? deg[i] : 0;
    sm[t] = v;
    __syncthreads();
    for (int off = 1; off < 1024; off <<= 1) {
        int u = (t >= off) ? sm[t - off] : 0;
        __syncthreads();
        sm[t] += u;
        __syncthreads();
    }
    if (i < Nn) {
        int rp = boff[blockIdx.x] + sm[t] - v;   // exclusive
        rowptr[i] = rp;
        invd[i] = 1.0f / (float)max(v, 1);
        if ((i & 127) == 0) cursor[i >> 7] = rp;
    }
    if (i == Nn) rowptr[Nn] = E;
}

// multisplit: tile -> LDS bucket-compaction -> contiguous packed-edge segments.
// bucket = dst>>7 (<=1024 buckets); payload = (dst&127)<<17 | src  (src < 2^17)
#define TILE 4096
#define MAXBK 1024
__global__ __launch_bounds__(512) void bucket_scatter(const int* __restrict__ src,
                                                      const int* __restrict__ dst,
                                                      int* __restrict__ cursor,
                                                      u32* __restrict__ pairs, int E) {
    __shared__ u32 sp_pl[TILE];                         // 16 KB
    __shared__ u16 sp_b[TILE];                          // 8 KB
    __shared__ int s_cnt[MAXBK], s_start[MAXBK], s_gpos[MAXBK], s_cnt2[MAXBK]; // 16 KB
    __shared__ int sm[512];                             // 2 KB
    const int tid = threadIdx.x;
    const int base = blockIdx.x * TILE;
    const int tn = min(TILE, E - base);
    s_cnt[tid] = 0; s_cnt[tid + 512] = 0;
    s_cnt2[tid] = 0; s_cnt2[tid + 512] = 0;
    __syncthreads();
    int d[8];
    u32 pl[8];
#pragma unroll
    for (int j = 0; j < 8; j++) {
        int k = tid + j * 512;
        if (k < tn) {
            d[j] = dst[base + k];
            pl[j] = (u32)((d[j] & 127) << 17) | (u32)src[base + k];
            atomicAdd(&s_cnt[d[j] >> 7], 1);
        } else d[j] = -1;
    }
    __syncthreads();
    // scan 1024 counters with 512 threads (2 each)
    int v0 = s_cnt[2 * tid], v1 = s_cnt[2 * tid + 1];
    sm[tid] = v0 + v1;
    __syncthreads();
    for (int off = 1; off < 512; off <<= 1) {
        int v = (tid >= off) ? sm[tid - off] : 0;
        __syncthreads();
        sm[tid] += v;
        __syncthreads();
    }
    int ex = sm[tid] - (v0 + v1);
    s_start[2 * tid] = ex;
    s_start[2 * tid + 1] = ex + v0;
    if (v0 > 0) s_gpos[2 * tid] = atomicAdd(&cursor[2 * tid], v0);
    if (v1 > 0) s_gpos[2 * tid + 1] = atomicAdd(&cursor[2 * tid + 1], v1);
    __syncthreads();
#pragma unroll
    for (int j = 0; j < 8; j++) {
        if (d[j] >= 0) {
            int b = d[j] >> 7;
            int p = atomicAdd(&s_cnt2[b], 1);
            int idx = s_start[b] + p;
            sp_pl[idx] = pl[j];
            sp_b[idx] = (u16)b;
        }
    }
    __syncthreads();
    for (int k = tid; k < tn; k += 512) {
        int b = sp_b[k];
        pairs[s_gpos[b] + (k - s_start[b])] = sp_pl[k];
    }
}

// ---------------- fused GEMM: C[M][NCOLS] = A[M][128] @ Bt^T  (bf16 in/out, fp32 acc) ----------------
#define KDIM 128
#define KP 136

template <int NCOLS>
__global__ __launch_bounds__(256) void gemm_bf16(const u16* __restrict__ A,
                                                 const u16* __restrict__ Bt,
                                                 u16* __restrict__ C, int M) {
    __shared__ u16 As[64 * KP];
    __shared__ u16 Bs[128 * KP];
    const int row0 = blockIdx.x * 64;
    const int col0 = blockIdx.y * 128;
    const int tid = threadIdx.x;

#pragma unroll
    for (int i = 0; i < 4; i++) {
        int idx = tid + i * 256;
        int r = idx >> 4, c = idx & 15;
        uint4 v = make_uint4(0, 0, 0, 0);
        if (row0 + r < M) v = ((const uint4*)(A + (size_t)(row0 + r) * KDIM))[c];
        ((uint4*)(As + r * KP))[c] = v;
    }
#pragma unroll
    for (int i = 0; i < 8; i++) {
        int idx = tid + i * 256;
        int r = idx >> 4, c = idx & 15;
        uint4 v = ((const uint4*)(Bt + (size_t)(col0 + r) * KDIM))[c];
        ((uint4*)(Bs + r * KP))[c] = v;
    }
    __syncthreads();

    const int lane = tid & 63, wave = tid >> 6;
    const int quad = lane >> 4, l16 = lane & 15;
    const int wcol = wave * 32;

    f32x4 acc[4][2];
#pragma unroll
    for (int mt = 0; mt < 4; mt++)
#pragma unroll
        for (int nt = 0; nt < 2; nt++) acc[mt][nt] = (f32x4){0.f, 0.f, 0.f, 0.f};

#pragma unroll
    for (int kc = 0; kc < 4; kc++) {
        short8 a[4], b[2];
#pragma unroll
        for (int mt = 0; mt < 4; mt++)
            a[mt] = *(const short8*)(As + (size_t)(mt * 16 + l16) * KP + kc * 32 + quad * 8);
#pragma unroll
        for (int nt = 0; nt < 2; nt++)
            b[nt] = *(const short8*)(Bs + (size_t)(wcol + nt * 16 + l16) * KP + kc * 32 + quad * 8);
#pragma unroll
        for (int mt = 0; mt < 4; mt++)
#pragma unroll
            for (int nt = 0; nt < 2; nt++)
                acc[mt][nt] = __builtin_amdgcn_mfma_f32_16x16x32_bf16(a[mt], b[nt], acc[mt][nt], 0, 0, 0);
    }

#pragma unroll
    for (int mt = 0; mt < 4; mt++) {
#pragma unroll
        for (int i = 0; i < 4; i++) {
            int r = row0 + mt * 16 + quad * 4 + i;
            if (r < M) {
#pragma unroll
                for (int nt = 0; nt < 2; nt++)
                    C[(size_t)r * NCOLS + (col0 + wcol + nt * 16 + l16)] = f2bf(acc[mt][nt][i]);
            }
        }
    }
}

// ---------------- bucket-streaming aggregation with LDS fp32 accumulators ----------------
// One block per 128-node bucket; streams the bucket's packed edges densely.
// TC = t-columns (128 or 64); t at out2[.. + TOFF], row stride STRIDE (u16 units).
// acc layout swizzled: col c of node dl lives at acc[dl*TC + ((c + 4*dl) & (TC-1))].

__device__ __forceinline__ void acc8(float* a, int cb, int mask, uint4 v) {
    atomicAdd(&a[(cb + 0) & mask], bf2f(v.x & 0xffffu));
    atomicAdd(&a[(cb + 1) & mask], bf2f(v.x >> 16));
    atomicAdd(&a[(cb + 2) & mask], bf2f(v.y & 0xffffu));
    atomicAdd(&a[(cb + 3) & mask], bf2f(v.y >> 16));
    atomicAdd(&a[(cb + 4) & mask], bf2f(v.z & 0xffffu));
    atomicAdd(&a[(cb + 5) & mask], bf2f(v.z >> 16));
    atomicAdd(&a[(cb + 6) & mask], bf2f(v.w & 0xffffu));
    atomicAdd(&a[(cb + 7) & mask], bf2f(v.w >> 16));
}

template <int TC, int TOFF, int STRIDE, bool RELU, bool F32OUT>
__global__ __launch_bounds__(512) void agg_lds(const u16* __restrict__ out2,
                                               const int* __restrict__ rowptr,
                                               const u32* __restrict__ pairs,
                                               const float* __restrict__ invd,
                                               const float* __restrict__ bias,
                                               void* __restrict__ outp, int Nn) {
    __shared__ float acc[128 * TC];                     // 64 KB (TC=128) / 32 KB (TC=64)
    const int tid = threadIdx.x;
    const int n0 = blockIdx.x << 7;
    const int nd = min(128, Nn - n0);
    for (int i = tid; i < 128 * TC; i += 512) acc[i] = 0.f;
    const int base = rowptr[n0];
    const int end = rowptr[n0 + nd];
    __syncthreads();

    const int LPE = TC / 8;                             // lanes per edge (16 or 8)
    const int S = 64 / LPE;                             // edge slots per wave (4 or 8)
    const int wv = tid >> 6, ln = tid & 63;
    const int sl = ln / LPE, lg = ln % LPE;
    const u16* tb = out2 + TOFF + 8 * lg;
    const int cb = 8 * lg;
    const int mask = TC - 1;
    const int step = 8 * S;                             // edges per block per iteration

    int e = base + wv * S + sl;
    for (; e + step < end; e += 2 * step) {             // 2 independent gathers in flight
        u32 w0 = pairs[e], w1 = pairs[e + step];
        int d0 = w0 >> 17, s0 = w0 & 0x1ffff;
        int d1 = w1 >> 17, s1 = w1 & 0x1ffff;
        uint4 v0 = *(const uint4*)(tb + (size_t)s0 * STRIDE);
        uint4 v1 = *(const uint4*)(tb + (size_t)s1 * STRIDE);
        acc8(acc + d0 * TC, cb + 4 * d0, mask, v0);
        acc8(acc + d1 * TC, cb + 4 * d1, mask, v1);
    }
    for (; e < end; e += step) {
        u32 w = pairs[e];
        int d0 = w >> 17, s0 = w & 0x1ffff;
        uint4 v = *(const uint4*)(tb + (size_t)s0 * STRIDE);
        acc8(acc + d0 * TC, cb + 4 * d0, mask, v);
    }
    __syncthreads();

    if (!F32OUT) {
        // 128-col epilogue: bf16 out [Nn][128]
        for (int i = tid; i < nd * 16; i += 512) {
            int nl = i >> 4, g = i & 15, node = n0 + nl;
            int c0 = 8 * g, sw = 4 * nl;
            float id = invd[node];
            const float* ar = acc + nl * TC;
            uint4 sv = *(const uint4*)(out2 + (size_t)node * STRIDE + c0);
            u32 svw[4] = {sv.x, sv.y, sv.z, sv.w};
            u32 w[4];
#pragma unroll
            for (int h = 0; h < 4; h++) {
                int ca = c0 + 2 * h, cbn = c0 + 2 * h + 1;
                float oa = bf2f(svw[h] & 0xffffu) + ar[(ca + sw) & mask] * id + bias[ca];
                float ob = bf2f(svw[h] >> 16)     + ar[(cbn + sw) & mask] * id + bias[cbn];
                if (RELU) { oa = fmaxf(oa, 0.f); ob = fmaxf(ob, 0.f); }
                w[h] = (u32)f2bf(oa) | ((u32)f2bf(ob) << 16);
            }
            uint4 pk = make_uint4(w[0], w[1], w[2], w[3]);
            *(uint4*)((u16*)outp + (size_t)node * 128 + c0) = pk;
        }
    } else {
        // 64-col epilogue: fp32 out [Nn][47]
        for (int i = tid; i < nd * 8; i += 512) {
            int nl = i >> 3, g = i & 7, node = n0 + nl;
            int c0 = 8 * g, sw = 4 * nl;
            float id = invd[node];
            const float* ar = acc + nl * TC;
            uint4 sv = *(const uint4*)(out2 + (size_t)node * STRIDE + c0);
            u32 svw[4] = {sv.x, sv.y, sv.z, sv.w};
            float* orow = (float*)outp + (size_t)node * 47;
#pragma unroll
            for (int j = 0; j < 8; j++) {
                int c = c0 + j;
                if (c < 47) {
                    float s = bf2f((j & 1) ? (svw[j >> 1] >> 16) : (svw[j >> 1] & 0xffffu));
                    orow[c] = s + ar[(c + sw) & mask] * id + bias[c];
                }
            }
        }
    }
}

// ---------------- launch ----------------

extern "C" void kernel_launch(void* const* d_in, const int* in_sizes, int n_in,
                              void* d_out, int out_size, void* d_ws, size_t ws_size,
                              hipStream_t stream) {
    const float* x   = (const float*)d_in[0];
    const int*   src = (const int*)d_in[1];
    const int*   dst = (const int*)d_in[2];
    const float* ws0 = (const float*)d_in[3];
    const float* wn0 = (const float*)d_in[4];
    const float* b0  = (const float*)d_in[5];
    const float* ws1 = (const float*)d_in[6];
    const float* wn1 = (const float*)d_in[7];
    const float* b1  = (const float*)d_in[8];
    const float* ws2 = (const float*)d_in[9];
    const float* wn2 = (const float*)d_in[10];
    const float* b2  = (const float*)d_in[11];

    const int Nn = in_sizes[0] / 128;   // 100000
    const int E  = in_sizes[1];         // 1600000

    char* p = (char*)d_ws;
    auto alloc = [&](size_t bytes) -> void* {
        void* r = (void*)p;
        p += (bytes + 255) & ~(size_t)255;
        return r;
    };
    u16*   bufA   = (u16*)alloc((size_t)Nn * 128 * 2);   // x_bf16 / h1 / h2
    u16*   out2   = (u16*)alloc((size_t)Nn * 256 * 2);   // [s|t] per layer
    u16*   wt0    = (u16*)alloc(256 * 128 * 2);
    u16*   wt1    = (u16*)alloc(256 * 128 * 2);
    u16*   wt2    = (u16*)alloc(128 * 128 * 2);
    int*   deg    = (int*)alloc((size_t)Nn * 4);
    int*   rowptr = (int*)alloc((size_t)(Nn + 1) * 4);
    float* invd   = (float*)alloc((size_t)Nn * 4);
    u32*   pairs  = (u32*)alloc((size_t)E * 4);          // packed (dl<<17|src), persists all layers
    int*   bsum   = (int*)alloc(256 * 4);
    int*   boff   = (int*)alloc(256 * 4);
    int*   cursor = (int*)alloc(MAXBK * 4);

    hipMemsetAsync(deg, 0, (size_t)Nn * 4, stream);

    cvt_f2b<<<(Nn * 32 + 255) / 256, 256, 0, stream>>>(x, bufA, (size_t)Nn * 32);
    prep_w_all<<<320, 256, 0, stream>>>(ws0, wn0, wt0, ws1, wn1, wt1, ws2, wn2, wt2);

    hist_k<<<(E + 255) / 256, 256, 0, stream>>>(dst, deg, E);
    const int nb = (Nn + 1023) / 1024;
    const int nb2 = (Nn + 1 + 1023) / 1024;
    scan_partial<<<nb, 256, 0, stream>>>(deg, bsum, Nn);
    scan_offsets<<<1, 256, 0, stream>>>(bsum, boff, nb);
    scan_final<<<nb2, 1024, 0, stream>>>(deg, boff, rowptr, invd, cursor, Nn, E);

    bucket_scatter<<<(E + TILE - 1) / TILE, 512, 0, stream>>>(src, dst, cursor, pairs, E);

    const int NBK = (Nn + 127) / 128;   // 782
    dim3 ggrid((Nn + 63) / 64, 2);
    dim3 ggrid1((Nn + 63) / 64, 1);
    // layer 0
    gemm_bf16<256><<<ggrid, 256, 0, stream>>>(bufA, wt0, out2, Nn);
    agg_lds<128, 128, 256, true, false><<<NBK, 512, 0, stream>>>(out2, rowptr, pairs, invd, b0, bufA, Nn);
    // layer 1
    gemm_bf16<256><<<ggrid, 256, 0, stream>>>(bufA, wt1, out2, Nn);
    agg_lds<128, 128, 256, true, false><<<NBK, 512, 0, stream>>>(out2, rowptr, pairs, invd, b1, bufA, Nn);
    // layer 2: N=128 (48 self + 48 neigh, padded)
    gemm_bf16<128><<<ggrid1, 256, 0, stream>>>(bufA, wt2, out2, Nn);
    agg_lds<64, 64, 128, false, true><<<NBK, 512, 0, stream>>>(out2, rowptr, pairs, invd, b2, d_out, Nn);
}

// Round 7
// 462.919 us; speedup vs baseline: 7.7973x; 7.7973x over previous
//
#include <hip/hip_runtime.h>

typedef unsigned int u32;
typedef unsigned short u16;
typedef __attribute__((ext_vector_type(8))) short short8;   // 8 x bf16 (guide-verified frag type)
typedef __attribute__((ext_vector_type(4))) float f32x4;

__device__ __forceinline__ u16 f2bf(float f) {
    u32 u = __float_as_uint(f);
    u32 r = (u + 0x7fffu + ((u >> 16) & 1u)) >> 16;   // RNE
    return (u16)r;
}
__device__ __forceinline__ float bf2f(u32 lo16) { return __uint_as_float(lo16 << 16); }

// ---------------- prep ----------------

// fused transposed weights for all 3 layers in one launch
__global__ __launch_bounds__(256) void prep_w_all(const float* __restrict__ ws0, const float* __restrict__ wn0, u16* __restrict__ wt0,
                                                  const float* __restrict__ ws1, const float* __restrict__ wn1, u16* __restrict__ wt1,
                                                  const float* __restrict__ ws2, const float* __restrict__ wn2, u16* __restrict__ wt2) {
    int bid = blockIdx.x;
    const float *ws, *wn;
    u16* wt;
    int dout, HW, local;
    if (bid < 128)      { ws = ws0; wn = wn0; wt = wt0; dout = 128; HW = 128; local = bid; }
    else if (bid < 256) { ws = ws1; wn = wn1; wt = wt1; dout = 128; HW = 128; local = bid - 128; }
    else                { ws = ws2; wn = wn2; wt = wt2; dout = 47;  HW = 64;  local = bid - 256; }
    int idx = local * 256 + threadIdx.x;   // idx = n*128 + k
    int n = idx >> 7, k = idx & 127;
    float v = 0.f;
    if (n < HW) { if (n < dout) v = ws[k * dout + n]; }
    else { int nn = n - HW; if (nn < dout) v = wn[k * dout + nn]; }
    wt[idx] = f2bf(v);
}

// ---------------- CSR build ----------------

__global__ __launch_bounds__(256) void hist_k(const int* __restrict__ dst,
                                              int* __restrict__ deg, int E) {
    int i = blockIdx.x * 256 + threadIdx.x;
    if (i < E) atomicAdd(&deg[dst[i]], 1);
}

__global__ __launch_bounds__(256) void scan_partial(const int* __restrict__ deg,
                                                    int* __restrict__ bsum, int Nn) {
    __shared__ int sm[256];
    int t = threadIdx.x;
    int base = blockIdx.x * 1024 + t * 4;
    int s = 0;
#pragma unroll
    for (int j = 0; j < 4; j++)
        if (base + j < Nn) s += deg[base + j];
    sm[t] = s;
    __syncthreads();
    for (int off = 128; off > 0; off >>= 1) {
        if (t < off) sm[t] += sm[t + off];
        __syncthreads();
    }
    if (t == 0) bsum[blockIdx.x] = sm[0];
}

__global__ __launch_bounds__(256) void scan_offsets(const int* __restrict__ bsum,
                                                    int* __restrict__ boff, int nb) {
    __shared__ int sm[256];
    int t = threadIdx.x;
    int v = (t < nb) ? bsum[t] : 0;
    sm[t] = v;
    __syncthreads();
    for (int off = 1; off < 256; off <<= 1) {
        int u = (t >= off) ? sm[t - off] : 0;
        __syncthreads();
        sm[t] += u;
        __syncthreads();
    }
    if (t < nb) boff[t] = sm[t] - v;
}

// rowptr + invd + bucket cursor init (cursor[b] = rowptr[b*512])
__global__ __launch_bounds__(1024) void scan_final(const int* __restrict__ deg,
                                                   const int* __restrict__ boff,
                                                   int* __restrict__ rowptr,
                                                   float* __restrict__ invd,
                                                   int* __restrict__ cursor,
                                                   int Nn, int E) {
    __shared__ int sm[1024];
    int t = threadIdx.x;
    int i = blockIdx.x * 1024 + t;
    int v = (i < Nn) ? deg[i] : 0;
    sm[t] = v;
    __syncthreads();
    for (int off = 1; off < 1024; off <<= 1) {
        int u = (t >= off) ? sm[t - off] : 0;
        __syncthreads();
        sm[t] += u;
        __syncthreads();
    }
    if (i < Nn) {
        int rp = boff[blockIdx.x] + sm[t] - v;   // exclusive
        rowptr[i] = rp;
        invd[i] = 1.0f / (float)max(v, 1);
        if ((i & 511) == 0) cursor[i >> 9] = rp;
    }
    if (i == Nn) rowptr[Nn] = E;
}

// multisplit pass 1: tile -> LDS bucket-compaction -> contiguous bucket segments
#define TILE 4096
__global__ __launch_bounds__(512) void bucket_scatter(const int* __restrict__ src,
                                                      const int* __restrict__ dst,
                                                      int* __restrict__ cursor,
                                                      uint2* __restrict__ pairs, int E) {
    __shared__ uint2 sp[TILE];                         // 32 KB
    __shared__ int s_cnt[256], s_off[256], s_gpos[256], s_cnt2[256];
    const int tid = threadIdx.x;
    const int base = blockIdx.x * TILE;
    const int tn = min(TILE, E - base);
    if (tid < 256) { s_cnt[tid] = 0; s_cnt2[tid] = 0; }
    __syncthreads();
    int d[8], s[8];
#pragma unroll
    for (int j = 0; j < 8; j++) {
        int k = tid + j * 512;
        if (k < tn) {
            d[j] = dst[base + k];
            s[j] = src[base + k];
            atomicAdd(&s_cnt[d[j] >> 9], 1);
        } else d[j] = -1;
    }
    __syncthreads();
    if (tid < 256) s_off[tid] = s_cnt[tid];
    __syncthreads();
    for (int off = 1; off < 256; off <<= 1) {
        int v = 0;
        if (tid < 256 && tid >= off) v = s_off[tid - off];
        __syncthreads();
        if (tid < 256) s_off[tid] += v;
        __syncthreads();
    }
    if (tid < 256 && s_cnt[tid] > 0) s_gpos[tid] = atomicAdd(&cursor[tid], s_cnt[tid]);
    __syncthreads();
#pragma unroll
    for (int j = 0; j < 8; j++) {
        if (d[j] >= 0) {
            int b = d[j] >> 9;
            int p = atomicAdd(&s_cnt2[b], 1);
            sp[s_off[b] - s_cnt[b] + p] = make_uint2((u32)d[j], (u32)s[j]);
        }
    }
    __syncthreads();
    for (int k = tid; k < tn; k += 512) {
        uint2 pr = sp[k];
        int b = (int)(pr.x >> 9);
        pairs[s_gpos[b] + (k - (s_off[b] - s_cnt[b]))] = pr;
    }
}

// multisplit pass 2: per-bucket exact CSR placement via LDS counters, coalesced writeback
#define LDSCAP 12288
__global__ __launch_bounds__(512) void build_csr(const uint2* __restrict__ pairs,
                                                 const int* __restrict__ rowptr,
                                                 int* __restrict__ cols, int Nn) {
    __shared__ int s_cols[LDSCAP];                     // 48 KB
    __shared__ int s_row[513];
    __shared__ int s_cnt[512];
    const int tid = threadIdx.x;
    const int d0 = blockIdx.x * 512;
    const int nd = min(512, Nn - d0);
    for (int i = tid; i <= nd; i += 512) s_row[i] = rowptr[d0 + i];
    if (tid < nd) s_cnt[tid] = 0;
    __syncthreads();
    const int base = s_row[0];
    const int n = s_row[nd] - base;
    const bool fit = (n <= LDSCAP);
    for (int k = tid; k < n; k += 512) {
        uint2 pr = pairs[base + k];
        int dl = (int)pr.x - d0;
        int p = atomicAdd(&s_cnt[dl], 1);
        int pos = s_row[dl] - base + p;
        if (fit) s_cols[pos] = (int)pr.y;
        else cols[base + pos] = (int)pr.y;             // overflow fallback (never expected)
    }
    __syncthreads();
    if (fit)
        for (int k = tid; k < n; k += 512) cols[base + k] = s_cols[k];
}

// ---------------- fused GEMM: C[M][NCOLS] = A[M][128] @ Bt^T  (fp32 acc) ----------------
// AF32: A is fp32 (layer 0 reads x directly, converts during LDS staging).
#define KDIM 128
#define KP 136

template <int NCOLS, bool AF32>
__global__ __launch_bounds__(256) void gemm_bf16(const void* __restrict__ Ap,
                                                 const u16* __restrict__ Bt,
                                                 u16* __restrict__ C, int M) {
    __shared__ u16 As[64 * KP];
    __shared__ u16 Bs[128 * KP];
    const int row0 = blockIdx.x * 64;
    const int col0 = blockIdx.y * 128;
    const int tid = threadIdx.x;

#pragma unroll
    for (int i = 0; i < 4; i++) {
        int idx = tid + i * 256;
        int r = idx >> 4, c = idx & 15;
        uint4 v = make_uint4(0, 0, 0, 0);
        if (row0 + r < M) {
            if (AF32) {
                const float* Af = (const float*)Ap;
                const float4* rowp = (const float4*)(Af + (size_t)(row0 + r) * KDIM);
                float4 f0 = rowp[2 * c];
                float4 f1 = rowp[2 * c + 1];
                v.x = (u32)f2bf(f0.x) | ((u32)f2bf(f0.y) << 16);
                v.y = (u32)f2bf(f0.z) | ((u32)f2bf(f0.w) << 16);
                v.z = (u32)f2bf(f1.x) | ((u32)f2bf(f1.y) << 16);
                v.w = (u32)f2bf(f1.z) | ((u32)f2bf(f1.w) << 16);
            } else {
                const u16* Ab = (const u16*)Ap;
                v = ((const uint4*)(Ab + (size_t)(row0 + r) * KDIM))[c];
            }
        }
        ((uint4*)(As + r * KP))[c] = v;
    }
#pragma unroll
    for (int i = 0; i < 8; i++) {
        int idx = tid + i * 256;
        int r = idx >> 4, c = idx & 15;
        uint4 v = ((const uint4*)(Bt + (size_t)(col0 + r) * KDIM))[c];
        ((uint4*)(Bs + r * KP))[c] = v;
    }
    __syncthreads();

    const int lane = tid & 63, wave = tid >> 6;
    const int quad = lane >> 4, l16 = lane & 15;
    const int wcol = wave * 32;

    f32x4 acc[4][2];
#pragma unroll
    for (int mt = 0; mt < 4; mt++)
#pragma unroll
        for (int nt = 0; nt < 2; nt++) acc[mt][nt] = (f32x4){0.f, 0.f, 0.f, 0.f};

#pragma unroll
    for (int kc = 0; kc < 4; kc++) {
        short8 a[4], b[2];
#pragma unroll
        for (int mt = 0; mt < 4; mt++)
            a[mt] = *(const short8*)(As + (size_t)(mt * 16 + l16) * KP + kc * 32 + quad * 8);
#pragma unroll
        for (int nt = 0; nt < 2; nt++)
            b[nt] = *(const short8*)(Bs + (size_t)(wcol + nt * 16 + l16) * KP + kc * 32 + quad * 8);
#pragma unroll
        for (int mt = 0; mt < 4; mt++)
#pragma unroll
            for (int nt = 0; nt < 2; nt++)
                acc[mt][nt] = __builtin_amdgcn_mfma_f32_16x16x32_bf16(a[mt], b[nt], acc[mt][nt], 0, 0, 0);
    }

    // C/D layout: col = lane&15, row = quad*4 + reg   [verified m89/m91]
#pragma unroll
    for (int mt = 0; mt < 4; mt++) {
#pragma unroll
        for (int i = 0; i < 4; i++) {
            int r = row0 + mt * 16 + quad * 4 + i;
            if (r < M) {
#pragma unroll
                for (int nt = 0; nt < 2; nt++)
                    C[(size_t)r * NCOLS + (col0 + wcol + nt * 16 + l16)] = f2bf(acc[mt][nt][i]);
            }
        }
    }
}

// ---------------- 128-col aggregation: 4 edges/wave, uint4 gathers, x2 unroll ----------------
// out2 = [M][256] bf16 (s | t).  outp = [M][128] bf16.
template <bool RELU>
__global__ __launch_bounds__(256) void agg128_k(const u16* __restrict__ out2,
                                                const int* __restrict__ rowptr,
                                                const int* __restrict__ cols,
                                                const float* __restrict__ invd,
                                                const float* __restrict__ bias,
                                                u16* __restrict__ outp, int Mn) {
    int wave = threadIdx.x >> 6, lane = threadIdx.x & 63;
    int node = blockIdx.x * 4 + wave;
    if (node >= Mn) return;
    int sub = lane >> 4, l16 = lane & 15;
    int beg = rowptr[node], end = rowptr[node + 1];
    float a[8] = {0.f, 0.f, 0.f, 0.f, 0.f, 0.f, 0.f, 0.f};
    const u16* tb = out2 + 128 + 8 * l16;
    int e = beg + sub;
    for (; e + 4 < end; e += 8) {                       // 2 independent gathers in flight
        int s0 = cols[e], s1 = cols[e + 4];
        uint4 v0 = *(const uint4*)(tb + (size_t)s0 * 256);
        uint4 v1 = *(const uint4*)(tb + (size_t)s1 * 256);
        a[0] += bf2f(v0.x & 0xffffu) + bf2f(v1.x & 0xffffu);
        a[1] += bf2f(v0.x >> 16)     + bf2f(v1.x >> 16);
        a[2] += bf2f(v0.y & 0xffffu) + bf2f(v1.y & 0xffffu);
        a[3] += bf2f(v0.y >> 16)     + bf2f(v1.y >> 16);
        a[4] += bf2f(v0.z & 0xffffu) + bf2f(v1.z & 0xffffu);
        a[5] += bf2f(v0.z >> 16)     + bf2f(v1.z >> 16);
        a[6] += bf2f(v0.w & 0xffffu) + bf2f(v1.w & 0xffffu);
        a[7] += bf2f(v0.w >> 16)     + bf2f(v1.w >> 16);
    }
    if (e < end) {
        uint4 v = *(const uint4*)(tb + (size_t)cols[e] * 256);
        a[0] += bf2f(v.x & 0xffffu); a[1] += bf2f(v.x >> 16);
        a[2] += bf2f(v.y & 0xffffu); a[3] += bf2f(v.y >> 16);
        a[4] += bf2f(v.z & 0xffffu); a[5] += bf2f(v.z >> 16);
        a[6] += bf2f(v.w & 0xffffu); a[7] += bf2f(v.w >> 16);
    }
#pragma unroll
    for (int j = 0; j < 8; j++) {
        a[j] += __shfl_xor(a[j], 32);
        a[j] += __shfl_xor(a[j], 16);
    }
    if (lane < 16) {
        float id = invd[node];
        uint4 sv = *(const uint4*)(out2 + (size_t)node * 256 + 8 * l16);
        float4 b0 = *(const float4*)(bias + 8 * l16);
        float4 b1 = *(const float4*)(bias + 8 * l16 + 4);
        float o0 = bf2f(sv.x & 0xffffu) + a[0] * id + b0.x;
        float o1 = bf2f(sv.x >> 16)     + a[1] * id + b0.y;
        float o2 = bf2f(sv.y & 0xffffu) + a[2] * id + b0.z;
        float o3 = bf2f(sv.y >> 16)     + a[3] * id + b0.w;
        float o4 = bf2f(sv.z & 0xffffu) + a[4] * id + b1.x;
        float o5 = bf2f(sv.z >> 16)     + a[5] * id + b1.y;
        float o6 = bf2f(sv.w & 0xffffu) + a[6] * id + b1.z;
        float o7 = bf2f(sv.w >> 16)     + a[7] * id + b1.w;
        if (RELU) {
            o0 = fmaxf(o0, 0.f); o1 = fmaxf(o1, 0.f); o2 = fmaxf(o2, 0.f); o3 = fmaxf(o3, 0.f);
            o4 = fmaxf(o4, 0.f); o5 = fmaxf(o5, 0.f); o6 = fmaxf(o6, 0.f); o7 = fmaxf(o7, 0.f);
        }
        uint4 w;
        w.x = (u32)f2bf(o0) | ((u32)f2bf(o1) << 16);
        w.y = (u32)f2bf(o2) | ((u32)f2bf(o3) << 16);
        w.z = (u32)f2bf(o4) | ((u32)f2bf(o5) << 16);
        w.w = (u32)f2bf(o6) | ((u32)f2bf(o7) << 16);
        *(uint4*)(outp + (size_t)node * 128 + 8 * l16) = w;
    }
}

// ---------------- layer-2 aggregation: 8 edges/wave, uint4 gathers, fp32 out ----------------
// out2 = [M][128] bf16: s at cols 0..63 (live 0..46), t at cols 64..127 (live 64..110).
__global__ __launch_bounds__(256) void agg_out8_k(const u16* __restrict__ out2,
                                                  const int* __restrict__ rowptr,
                                                  const int* __restrict__ cols,
                                                  const float* __restrict__ invd,
                                                  const float* __restrict__ bias,
                                                  float* __restrict__ outp, int Mn) {
    int wave = threadIdx.x >> 6, lane = threadIdx.x & 63;
    int node = blockIdx.x * 4 + wave;
    if (node >= Mn) return;
    int e8 = lane >> 3, l8 = lane & 7;                  // 8 edge slots x 8 lanes
    int beg = rowptr[node], end = rowptr[node + 1];
    float a[8] = {0.f, 0.f, 0.f, 0.f, 0.f, 0.f, 0.f, 0.f};
    const u16* tb = out2 + 64 + 8 * l8;                 // lane covers cols 8*l8..8*l8+7 of t
    int e = beg + e8;
    for (; e + 8 < end; e += 16) {                      // 2 independent gathers in flight
        int s0 = cols[e], s1 = cols[e + 8];
        uint4 v0 = *(const uint4*)(tb + (size_t)s0 * 128);
        uint4 v1 = *(const uint4*)(tb + (size_t)s1 * 128);
        a[0] += bf2f(v0.x & 0xffffu) + bf2f(v1.x & 0xffffu);
        a[1] += bf2f(v0.x >> 16)     + bf2f(v1.x >> 16);
        a[2] += bf2f(v0.y & 0xffffu) + bf2f(v1.y & 0xffffu);
        a[3] += bf2f(v0.y >> 16)     + bf2f(v1.y >> 16);
        a[4] += bf2f(v0.z & 0xffffu) + bf2f(v1.z & 0xffffu);
        a[5] += bf2f(v0.z >> 16)     + bf2f(v1.z >> 16);
        a[6] += bf2f(v0.w & 0xffffu) + bf2f(v1.w & 0xffffu);
        a[7] += bf2f(v0.w >> 16)     + bf2f(v1.w >> 16);
    }
    if (e < end) {
        uint4 v = *(const uint4*)(tb + (size_t)cols[e] * 128);
        a[0] += bf2f(v.x & 0xffffu); a[1] += bf2f(v.x >> 16);
        a[2] += bf2f(v.y & 0xffffu); a[3] += bf2f(v.y >> 16);
        a[4] += bf2f(v.z & 0xffffu); a[5] += bf2f(v.z >> 16);
        a[6] += bf2f(v.w & 0xffffu); a[7] += bf2f(v.w >> 16);
    }
#pragma unroll
    for (int j = 0; j < 8; j++) {                       // reduce across the 8 edge slots
        a[j] += __shfl_xor(a[j], 8);
        a[j] += __shfl_xor(a[j], 16);
        a[j] += __shfl_xor(a[j], 32);
    }
    if (lane < 8) {                                     // lane l8 holds cols 8*l8..8*l8+7
        float id = invd[node];
        uint4 sv = *(const uint4*)(out2 + (size_t)node * 128 + 8 * l8);
        u32 sw[4] = {sv.x, sv.y, sv.z, sv.w};
        float* orow = outp + (size_t)node * 47;
#pragma unroll
        for (int j = 0; j < 8; j++) {
            int c = 8 * l8 + j;
            if (c < 47) {
                float s = bf2f((j & 1) ? (sw[j >> 1] >> 16) : (sw[j >> 1] & 0xffffu));
                orow[c] = s + a[j] * id + bias[c];
            }
        }
    }
}

// ---------------- launch ----------------

extern "C" void kernel_launch(void* const* d_in, const int* in_sizes, int n_in,
                              void* d_out, int out_size, void* d_ws, size_t ws_size,
                              hipStream_t stream) {
    const float* x   = (const float*)d_in[0];
    const int*   src = (const int*)d_in[1];
    const int*   dst = (const int*)d_in[2];
    const float* ws0 = (const float*)d_in[3];
    const float* wn0 = (const float*)d_in[4];
    const float* b0  = (const float*)d_in[5];
    const float* ws1 = (const float*)d_in[6];
    const float* wn1 = (const float*)d_in[7];
    const float* b1  = (const float*)d_in[8];
    const float* ws2 = (const float*)d_in[9];
    const float* wn2 = (const float*)d_in[10];
    const float* b2  = (const float*)d_in[11];

    const int Nn = in_sizes[0] / 128;   // 100000
    const int E  = in_sizes[1];         // 1600000

    char* p = (char*)d_ws;
    auto alloc = [&](size_t bytes) -> void* {
        void* r = (void*)p;
        p += (bytes + 255) & ~(size_t)255;
        return r;
    };
    u16*   bufA   = (u16*)alloc((size_t)Nn * 128 * 2);   // h1 / h2
    u16*   out2   = (u16*)alloc((size_t)Nn * 256 * 2);   // [s|t] per layer; ALSO overlaid as pairs buf
    u16*   wt0    = (u16*)alloc(256 * 128 * 2);
    u16*   wt1    = (u16*)alloc(256 * 128 * 2);
    u16*   wt2    = (u16*)alloc(128 * 128 * 2);
    int*   deg    = (int*)alloc((size_t)Nn * 4);
    int*   rowptr = (int*)alloc((size_t)(Nn + 1) * 4);
    float* invd   = (float*)alloc((size_t)Nn * 4);
    int*   cols   = (int*)alloc((size_t)E * 4);
    int*   bsum   = (int*)alloc(256 * 4);
    int*   boff   = (int*)alloc(256 * 4);
    int*   cursor = (int*)alloc(256 * 4);
    uint2* pairs  = (uint2*)out2;                        // overlay: out2 unused until gemm layer 0

    hipMemsetAsync(deg, 0, (size_t)Nn * 4, stream);

    prep_w_all<<<320, 256, 0, stream>>>(ws0, wn0, wt0, ws1, wn1, wt1, ws2, wn2, wt2);

    hist_k<<<(E + 255) / 256, 256, 0, stream>>>(dst, deg, E);
    const int nb = (Nn + 1023) / 1024;
    const int nb2 = (Nn + 1 + 1023) / 1024;
    scan_partial<<<nb, 256, 0, stream>>>(deg, bsum, Nn);
    scan_offsets<<<1, 256, 0, stream>>>(bsum, boff, nb);
    scan_final<<<nb2, 1024, 0, stream>>>(deg, boff, rowptr, invd, cursor, Nn, E);

    bucket_scatter<<<(E + TILE - 1) / TILE, 512, 0, stream>>>(src, dst, cursor, pairs, E);
    build_csr<<<(Nn + 511) / 512, 512, 0, stream>>>(pairs, rowptr, cols, Nn);

    dim3 ggrid((Nn + 63) / 64, 2);
    dim3 ggrid1((Nn + 63) / 64, 1);
    // layer 0: GEMM reads x fp32 directly (cvt fused into staging)
    gemm_bf16<256, true><<<ggrid, 256, 0, stream>>>(x, wt0, out2, Nn);
    agg128_k<true><<<(Nn + 3) / 4, 256, 0, stream>>>(out2, rowptr, cols, invd, b0, bufA, Nn);
    // layer 1
    gemm_bf16<256, false><<<ggrid, 256, 0, stream>>>(bufA, wt1, out2, Nn);
    agg128_k<true><<<(Nn + 3) / 4, 256, 0, stream>>>(out2, rowptr, cols, invd, b1, bufA, Nn);
    // layer 2: N=128 (48 self + 48 neigh, padded)
    gemm_bf16<128, false><<<ggrid1, 256, 0, stream>>>(bufA, wt2, out2, Nn);
    agg_out8_k<<<(Nn + 3) / 4, 256, 0, stream>>>(out2, rowptr, cols, invd, b2, (float*)d_out, Nn);
}